// Round 1
// baseline (6417.062 us; speedup 1.0000x reference)
//
#include <hip/hip_runtime.h>
#include <stdint.h>

#define B_ 128
#define T_ 256
#define F_ 128
#define NCAT_ 32
#define CARD_ 16
#define E_ 8
#define H_ 512
#define INLEN_ 352
#define NCONT_ 96

typedef __bf16 bf16x8 __attribute__((ext_vector_type(8)));
typedef float f32x4 __attribute__((ext_vector_type(4)));
typedef unsigned short ushortx8 __attribute__((ext_vector_type(8)));

__device__ __forceinline__ unsigned short f2bf(float f) {
  unsigned int u = __float_as_uint(f);
  u += 0x7fffu + ((u >> 16) & 1u);   // RNE
  return (unsigned short)(u >> 16);
}
__device__ __forceinline__ float sigm(float x) { return 1.0f / (1.0f + __expf(-x)); }
__device__ __forceinline__ float tanhf_(float x) {
  float a = fabsf(x);
  float e = __expf(-2.0f * a);
  float t = (1.0f - e) / (1.0f + e);
  return x < 0.0f ? -t : t;
}

// ---------------- init: zero h ping-pong buffer B and barrier ctrl ----------------
__global__ void k_init(unsigned int* bufB_u32, unsigned int* ctrl) {
  if (blockIdx.x < 128) {
    bufB_u32[blockIdx.x * 256 + threadIdx.x] = 0u;  // 32768 u32 = 128*512 bf16
  } else {
    ctrl[threadIdx.x] = 0u;
  }
}

// ---------------- prep: W_in transposed -> bf16 (512 x 352) ----------------
__global__ void k_prep(const float* __restrict__ W_in, unsigned short* __restrict__ W_inT) {
  int id = blockIdx.x * 256 + threadIdx.x;
  if (id < 512 * INLEN_) {
    int n = id / INLEN_;
    int k = id - n * INLEN_;
    W_inT[id] = f2bf(W_in[k * 512 + n]);
  }
}

// ---------------- features: FEAT[t*128+b][352] bf16 ----------------
__global__ void k_feat(const int* __restrict__ unscaled, const float* __restrict__ scaled,
                       const float* __restrict__ emb, unsigned short* __restrict__ FEAT) {
  int row = blockIdx.x * 4 + (threadIdx.x >> 6);
  int t = row >> 7, b = row & 127;
  const int base = (b * T_ + t) * F_;
  for (int jj = (threadIdx.x & 63); jj < INLEN_; jj += 64) {
    int ci = jj / 11;
    int pos = jj - ci * 11;
    float v;
    if (pos < 8) {
      int cid = unscaled[base + 4 * ci];
      v = emb[(ci * CARD_ + cid) * E_ + pos];
    } else {
      v = scaled[base + 4 * ci + 1 + (pos - 8)];
    }
    FEAT[row * INLEN_ + jj] = f2bf(v);
  }
}

// ---------------- GEMM1: X = relu(FEAT @ W_in + b_in), bf16 out ----------------
__global__ __launch_bounds__(256) void k_gemm1(const unsigned short* __restrict__ FEAT,
                                               const unsigned short* __restrict__ W_inT,
                                               const float* __restrict__ b_in,
                                               unsigned short* __restrict__ X) {
  __shared__ __align__(16) unsigned short As[128 * 40];
  __shared__ __align__(16) unsigned short Bs[128 * 40];
  const int tid = threadIdx.x;
  const int Mtile = blockIdx.x >> 2;
  const int N0 = (blockIdx.x & 3) * 128;
  const int wv = tid >> 6, ln = tid & 63;
  const int lrow = ln & 15, lq = ln >> 4;
  f32x4 acc[2][8];
#pragma unroll
  for (int i = 0; i < 2; ++i)
#pragma unroll
    for (int j = 0; j < 8; ++j) acc[i][j] = (f32x4){0.f, 0.f, 0.f, 0.f};

  for (int kc = 0; kc < 11; ++kc) {
    int k0 = kc * 32;
#pragma unroll
    for (int i = 0; i < 2; ++i) {
      int c = i * 256 + tid;          // 512 chunks of 8 shorts, for each of A and B
      int row = c >> 2;               // 4 chunks per 32-short row
      int col = (c & 3) * 8;
      uint4 va = *(const uint4*)&FEAT[(Mtile * 128 + row) * INLEN_ + k0 + col];
      *(uint4*)&As[row * 40 + col] = va;
      uint4 vb = *(const uint4*)&W_inT[(N0 + row) * INLEN_ + k0 + col];
      *(uint4*)&Bs[row * 40 + col] = vb;
    }
    __syncthreads();
    bf16x8 af[2];
#pragma unroll
    for (int mt = 0; mt < 2; ++mt) {
      int r = wv * 32 + mt * 16 + lrow;
      af[mt] = __builtin_bit_cast(bf16x8, *(const ushortx8*)&As[r * 40 + lq * 8]);
    }
#pragma unroll
    for (int ntl = 0; ntl < 8; ++ntl) {
      bf16x8 bf = __builtin_bit_cast(bf16x8, *(const ushortx8*)&Bs[(ntl * 16 + lrow) * 40 + lq * 8]);
      acc[0][ntl] = __builtin_amdgcn_mfma_f32_16x16x32_bf16(af[0], bf, acc[0][ntl], 0, 0, 0);
      acc[1][ntl] = __builtin_amdgcn_mfma_f32_16x16x32_bf16(af[1], bf, acc[1][ntl], 0, 0, 0);
    }
    __syncthreads();
  }
#pragma unroll
  for (int mt = 0; mt < 2; ++mt)
#pragma unroll
    for (int ntl = 0; ntl < 8; ++ntl) {
      int n = N0 + ntl * 16 + lrow;
      float bias = b_in[n];
#pragma unroll
      for (int r = 0; r < 4; ++r) {
        int row = Mtile * 128 + wv * 32 + mt * 16 + lq * 4 + r;
        float v = acc[mt][ntl][r] + bias;
        v = v > 0.0f ? v : 0.0f;
        X[row * H_ + n] = f2bf(v);
      }
    }
}

// ---------------- persistent LSTM ----------------
__device__ __forceinline__ void stage32(unsigned short* aS, const unsigned short* src, int tid) {
  // 32 rows x 512 shorts (row stride 512 in src, 520 in LDS)
#pragma unroll
  for (int i = 0; i < 8; ++i) {
    int c = i * 256 + tid;   // 2048 chunks of 8 shorts
    int row = c >> 6;
    int col = (c & 63) * 8;
    uint4 v = *(const uint4*)&src[row * H_ + col];
    *(uint4*)&aS[row * 520 + col] = v;
  }
}

__device__ __forceinline__ void barrier_sync(unsigned int* ctr, unsigned int* gen,
                                             unsigned int expect) {
  __syncthreads();   // drains each wave's vmcnt: all WG stores are in L2
  if (threadIdx.x == 0) {
    __builtin_amdgcn_fence(__ATOMIC_RELEASE, "agent");  // wbl2: flush dirty L2 to coherence point
    unsigned int old = __hip_atomic_fetch_add(ctr, 1u, __ATOMIC_RELAXED, __HIP_MEMORY_SCOPE_AGENT);
    if (old == 63u) {
      __hip_atomic_store(ctr, 0u, __ATOMIC_RELAXED, __HIP_MEMORY_SCOPE_AGENT);
      __hip_atomic_store(gen, expect, __ATOMIC_RELEASE, __HIP_MEMORY_SCOPE_AGENT);
    } else {
      int guard = 0;
      while (__hip_atomic_load(gen, __ATOMIC_RELAXED, __HIP_MEMORY_SCOPE_AGENT) < expect) {
        __builtin_amdgcn_s_sleep(2);
        if (++guard > 3000000) break;   // deadlock bail -> wrong answer instead of hang
      }
    }
    __builtin_amdgcn_fence(__ATOMIC_ACQUIRE, "agent");  // inv L1+L2: fresh reads of peers' h
  }
  __syncthreads();
}

__global__ __launch_bounds__(256, 1) void k_lstm(
    const float* __restrict__ Wih0, const float* __restrict__ Whh0,
    const float* __restrict__ bih0, const float* __restrict__ bhh0,
    const float* __restrict__ Wih1, const float* __restrict__ Whh1,
    const float* __restrict__ bih1, const float* __restrict__ bhh1,
    const unsigned short* __restrict__ X, unsigned short* __restrict__ bufA,
    unsigned short* __restrict__ bufB, unsigned int* ctrl,
    float* __restrict__ out_h, float* __restrict__ out_c) {
  __shared__ __align__(16) unsigned short aS[32 * 520];
  __shared__ __align__(16) float gS[32 * 36];
  __shared__ float hP[256];
  __shared__ float b0cS[32], b1cS[32];

  const int tid = threadIdx.x;
  const int quarter = blockIdx.x >> 6;   // batch quarter: rows r0..r0+31
  const int grp = blockIdx.x & 63;       // owns h-cols j0..j0+7 (gate cols q*512+j0+jj)
  const int j0 = grp * 8;
  const int r0 = quarter * 32;
  const int wv = tid >> 6, ln = tid & 63;
  const int lrow = ln & 15, lq = ln >> 4;
  const int mt = wv & 1, nt = wv >> 1;   // wave tile: rows mt*16.., gate-cols nt*16..
  const int n_local = nt * 16 + lrow;
  const int gcol = ((n_local >> 3) << 9) + j0 + (n_local & 7);  // q*512 + j0 + jj

  // one-time: weight B-fragments in registers (bf16), biases in LDS
  bf16x8 Bf0[32], Bf1[16];
  {
    const float* s0 = Wih0 + gcol * H_;
    const float* s1 = Whh0 + gcol * H_;
#pragma unroll
    for (int ks = 0; ks < 32; ++ks) {
      int k = ks * 32 + lq * 8;
      const float* s = (ks < 16) ? (s0 + k) : (s1 + (k - 512));
      ushortx8 u;
#pragma unroll
      for (int j = 0; j < 8; ++j) u[j] = f2bf(s[j]);
      Bf0[ks] = __builtin_bit_cast(bf16x8, u);
    }
    const float* sa = Wih1 + gcol * H_;
    const float* sb = Whh1 + gcol * H_;
#pragma unroll
    for (int ks = 0; ks < 16; ++ks) {
      int k = ks * 32 + lq * 8;
      ushortx8 u;
#pragma unroll
      for (int j = 0; j < 8; ++j) u[j] = f2bf(sa[k + j] + sb[k + j]);
      Bf1[ks] = __builtin_bit_cast(bf16x8, u);
    }
  }
  if (tid < 32) {
    int g2 = ((tid >> 3) << 9) + j0 + (tid & 7);
    b0cS[tid] = bih0[g2] + bhh0[g2];
    b1cS[tid] = bih1[g2] + bhh1[g2];
  }
  __syncthreads();

  unsigned int* ctr = ctrl + quarter * 64;
  unsigned int* gen = ctr + 32;

  const int eb = tid & 31, ej = tid >> 5;   // elementwise ownership: row eb, h-col ej
  float c_reg = 0.0f;
  float cp_v = 0.0f;
  const int fragOff = (mt * 16 + lrow) * 520 + lq * 8;

#pragma unroll 1
  for (int t = 0; t < T_; ++t) {
    // ---- cell 0: gates = x_t@Wih0^T + h@Whh0^T + b ----
    f32x4 acc = (f32x4){0.f, 0.f, 0.f, 0.f};
    stage32(aS, X + (t * B_ + r0) * H_, tid);
    __syncthreads();
#pragma unroll
    for (int ks = 0; ks < 16; ++ks) {
      bf16x8 a = __builtin_bit_cast(bf16x8, *(const ushortx8*)&aS[fragOff + ks * 32]);
      acc = __builtin_amdgcn_mfma_f32_16x16x32_bf16(a, Bf0[ks], acc, 0, 0, 0);
    }
    __syncthreads();
    stage32(aS, bufB + r0 * H_, tid);
    __syncthreads();
#pragma unroll
    for (int ks = 0; ks < 16; ++ks) {
      bf16x8 a = __builtin_bit_cast(bf16x8, *(const ushortx8*)&aS[fragOff + ks * 32]);
      acc = __builtin_amdgcn_mfma_f32_16x16x32_bf16(a, Bf0[16 + ks], acc, 0, 0, 0);
    }
    *(f32x4*)&gS[n_local * 36 + mt * 16 + lq * 4] = acc;
    __syncthreads();
    {
      float iv = gS[(ej) * 36 + eb] + b0cS[ej];
      float fv = gS[(8 + ej) * 36 + eb] + b0cS[8 + ej];
      float gv = gS[(16 + ej) * 36 + eb] + b0cS[16 + ej];
      float ov = gS[(24 + ej) * 36 + eb] + b0cS[24 + ej];
      cp_v = sigm(fv) * c_reg + sigm(iv) * tanhf_(gv);
      float hp_v = sigm(ov) * tanhf_(cp_v);
      hP[ej * 32 + eb] = hp_v;
    }
    __syncthreads();
    if (tid < 128) {
      int b = tid >> 2, p = tid & 3;
      unsigned int v = (unsigned int)f2bf(hP[(2 * p) * 32 + b]) |
                       ((unsigned int)f2bf(hP[(2 * p + 1) * 32 + b]) << 16);
      *(unsigned int*)&bufA[(r0 + b) * H_ + j0 + 2 * p] = v;
    }
    barrier_sync(ctr, gen, (unsigned int)(2 * t + 1));

    // ---- cell 1: gates = h'@(Wih1+Whh1)^T + b ----
    acc = (f32x4){0.f, 0.f, 0.f, 0.f};
    stage32(aS, bufA + r0 * H_, tid);
    __syncthreads();
#pragma unroll
    for (int ks = 0; ks < 16; ++ks) {
      bf16x8 a = __builtin_bit_cast(bf16x8, *(const ushortx8*)&aS[fragOff + ks * 32]);
      acc = __builtin_amdgcn_mfma_f32_16x16x32_bf16(a, Bf1[ks], acc, 0, 0, 0);
    }
    *(f32x4*)&gS[n_local * 36 + mt * 16 + lq * 4] = acc;
    __syncthreads();
    {
      float iv = gS[(ej) * 36 + eb] + b1cS[ej];
      float fv = gS[(8 + ej) * 36 + eb] + b1cS[8 + ej];
      float gv = gS[(16 + ej) * 36 + eb] + b1cS[16 + ej];
      float ov = gS[(24 + ej) * 36 + eb] + b1cS[24 + ej];
      float cn = sigm(fv) * cp_v + sigm(iv) * tanhf_(gv);
      float hn = sigm(ov) * tanhf_(cn);
      c_reg = cn;
      hP[ej * 32 + eb] = hn;
      if (t == T_ - 1) {
        out_h[(r0 + eb) * H_ + j0 + ej] = hn;
        out_c[(r0 + eb) * H_ + j0 + ej] = cn;
      }
    }
    __syncthreads();
    if (tid < 128) {
      int b = tid >> 2, p = tid & 3;
      unsigned int v = (unsigned int)f2bf(hP[(2 * p) * 32 + b]) |
                       ((unsigned int)f2bf(hP[(2 * p + 1) * 32 + b]) << 16);
      *(unsigned int*)&bufB[(r0 + b) * H_ + j0 + 2 * p] = v;
    }
    barrier_sync(ctr, gen, (unsigned int)(2 * t + 2));
  }
}

// ---------------- heads: cont_out + cls_out (f32) ----------------
__global__ __launch_bounds__(256) void k_heads(const float* __restrict__ h,
                                               const float* __restrict__ W_out,
                                               const float* __restrict__ b_out,
                                               const float* __restrict__ W_cls,
                                               const float* __restrict__ b_cls,
                                               float* __restrict__ out) {
  int o = blockIdx.x * 256 + threadIdx.x;   // 77824 total
  if (o < B_ * NCONT_) {
    int b = o / NCONT_;
    int n = o - b * NCONT_;
    float acc = b_out[n];
    const float* hb = h + b * H_;
    for (int k = 0; k < H_; k += 4) {
      acc += hb[k] * W_out[k * NCONT_ + n] + hb[k + 1] * W_out[(k + 1) * NCONT_ + n] +
             hb[k + 2] * W_out[(k + 2) * NCONT_ + n] + hb[k + 3] * W_out[(k + 3) * NCONT_ + n];
    }
    out[o] = acc;
  } else {
    int oo = o - B_ * NCONT_;
    int b = oo >> 9;
    int r = oo & 511;
    int ci = r >> 4, cd = r & 15;
    float acc = b_cls[ci * 16 + cd];
    const float* hb = h + b * H_;
    const float* wc = W_cls + ci * 512 * 16 + cd;
    for (int k = 0; k < H_; k += 4) {
      acc += hb[k] * wc[k * 16] + hb[k + 1] * wc[(k + 1) * 16] + hb[k + 2] * wc[(k + 2) * 16] +
             hb[k + 3] * wc[(k + 3) * 16];
    }
    out[B_ * NCONT_ + oo] = acc;
  }
}

extern "C" void kernel_launch(void* const* d_in, const int* in_sizes, int n_in,
                              void* d_out, int out_size, void* d_ws, size_t ws_size,
                              hipStream_t stream) {
  const int* unscaled = (const int*)d_in[0];
  const float* scaled = (const float*)d_in[1];
  const float* emb = (const float*)d_in[2];
  const float* W_in = (const float*)d_in[3];
  const float* b_in = (const float*)d_in[4];
  const float* Wih0 = (const float*)d_in[5];
  const float* Whh0 = (const float*)d_in[6];
  const float* bih0 = (const float*)d_in[7];
  const float* bhh0 = (const float*)d_in[8];
  const float* Wih1 = (const float*)d_in[9];
  const float* Whh1 = (const float*)d_in[10];
  const float* bih1 = (const float*)d_in[11];
  const float* bhh1 = (const float*)d_in[12];
  const float* W_out = (const float*)d_in[13];
  const float* b_out = (const float*)d_in[14];
  const float* W_cls = (const float*)d_in[15];
  const float* b_cls = (const float*)d_in[16];

  // workspace carve (bytes, 256-aligned)
  const size_t o_feat = 0;                       // 32768*352*2 = 23068672
  const size_t o_X = 23068672;                   // 32768*512*2 = 33554432
  const size_t o_WinT = 56623104;                // 512*352*2   = 360448
  const size_t o_bufA = 56983552;                // 128KB
  const size_t o_bufB = 57114624;                // 128KB
  const size_t o_ctrl = 57245696;                // 1KB
  const size_t WS_NEED = 57246720;
  if (ws_size < WS_NEED) return;                 // deterministic clean failure if ws too small

  char* ws = (char*)d_ws;
  unsigned short* FEAT = (unsigned short*)(ws + o_feat);
  unsigned short* X = (unsigned short*)(ws + o_X);
  unsigned short* W_inT = (unsigned short*)(ws + o_WinT);
  unsigned short* bufA = (unsigned short*)(ws + o_bufA);
  unsigned short* bufB = (unsigned short*)(ws + o_bufB);
  unsigned int* ctrl = (unsigned int*)(ws + o_ctrl);

  float* out = (float*)d_out;
  float* out_h = out + 77824;    // after cont_out(12288)+cls_out(65536)
  float* out_c = out + 143360;

  k_init<<<129, 256, 0, stream>>>((unsigned int*)bufB, ctrl);
  k_prep<<<704, 256, 0, stream>>>(W_in, W_inT);
  k_feat<<<8192, 256, 0, stream>>>(unscaled, scaled, emb, FEAT);
  k_gemm1<<<1024, 256, 0, stream>>>(FEAT, W_inT, b_in, X);
  k_lstm<<<256, 256, 0, stream>>>(Wih0, Whh0, bih0, bhh0, Wih1, Whh1, bih1, bhh1, X, bufA, bufB,
                                  ctrl, out_h, out_c);
  k_heads<<<304, 256, 0, stream>>>(out_h, W_out, b_out, W_cls, b_cls, out);
}

// Round 2
// 2190.606 us; speedup vs baseline: 2.9294x; 2.9294x over previous
//
#include <hip/hip_runtime.h>
#include <stdint.h>

#define B_ 128
#define T_ 256
#define F_ 128
#define NCAT_ 32
#define CARD_ 16
#define E_ 8
#define H_ 512
#define INLEN_ 352
#define NCONT_ 96

typedef __bf16 bf16x8 __attribute__((ext_vector_type(8)));
typedef float f32x4 __attribute__((ext_vector_type(4)));
typedef unsigned short ushortx8 __attribute__((ext_vector_type(8)));

__device__ __forceinline__ unsigned short f2bf(float f) {
  unsigned int u = __float_as_uint(f);
  u += 0x7fffu + ((u >> 16) & 1u);   // RNE
  return (unsigned short)(u >> 16);
}
__device__ __forceinline__ float sigm(float x) { return 1.0f / (1.0f + __expf(-x)); }
__device__ __forceinline__ float tanhf_(float x) {
  float a = fabsf(x);
  float e = __expf(-2.0f * a);
  float t = (1.0f - e) / (1.0f + e);
  return x < 0.0f ? -t : t;
}

// ---------------- init: zero h ping-pong buffer B and flags (agent-visible) ----------------
__global__ void k_init(unsigned int* bufB_u32, unsigned int* flags) {
  if (blockIdx.x < 128) {
    __hip_atomic_store(&bufB_u32[blockIdx.x * 256 + threadIdx.x], 0u, __ATOMIC_RELAXED,
                       __HIP_MEMORY_SCOPE_AGENT);
  } else {
    __hip_atomic_store(&flags[threadIdx.x], 0u, __ATOMIC_RELAXED, __HIP_MEMORY_SCOPE_AGENT);
  }
}

// ---------------- prep: W_in transposed -> bf16 (512 x 352) ----------------
__global__ void k_prep(const float* __restrict__ W_in, unsigned short* __restrict__ W_inT) {
  int id = blockIdx.x * 256 + threadIdx.x;
  if (id < 512 * INLEN_) {
    int n = id / INLEN_;
    int k = id - n * INLEN_;
    W_inT[id] = f2bf(W_in[k * 512 + n]);
  }
}

// ---------------- features: FEAT[t*128+b][352] bf16 ----------------
__global__ void k_feat(const int* __restrict__ unscaled, const float* __restrict__ scaled,
                       const float* __restrict__ emb, unsigned short* __restrict__ FEAT) {
  int row = blockIdx.x * 4 + (threadIdx.x >> 6);
  int t = row >> 7, b = row & 127;
  const int base = (b * T_ + t) * F_;
  for (int jj = (threadIdx.x & 63); jj < INLEN_; jj += 64) {
    int ci = jj / 11;
    int pos = jj - ci * 11;
    float v;
    if (pos < 8) {
      int cid = unscaled[base + 4 * ci];
      v = emb[(ci * CARD_ + cid) * E_ + pos];
    } else {
      v = scaled[base + 4 * ci + 1 + (pos - 8)];
    }
    FEAT[row * INLEN_ + jj] = f2bf(v);
  }
}

// ---------------- GEMM1: X = relu(FEAT @ W_in + b_in), bf16 out ----------------
__global__ __launch_bounds__(256) void k_gemm1(const unsigned short* __restrict__ FEAT,
                                               const unsigned short* __restrict__ W_inT,
                                               const float* __restrict__ b_in,
                                               unsigned short* __restrict__ X) {
  __shared__ __align__(16) unsigned short As[128 * 40];
  __shared__ __align__(16) unsigned short Bs[128 * 40];
  const int tid = threadIdx.x;
  const int Mtile = blockIdx.x >> 2;
  const int N0 = (blockIdx.x & 3) * 128;
  const int wv = tid >> 6, ln = tid & 63;
  const int lrow = ln & 15, lq = ln >> 4;
  f32x4 acc[2][8];
#pragma unroll
  for (int i = 0; i < 2; ++i)
#pragma unroll
    for (int j = 0; j < 8; ++j) acc[i][j] = (f32x4){0.f, 0.f, 0.f, 0.f};

  for (int kc = 0; kc < 11; ++kc) {
    int k0 = kc * 32;
#pragma unroll
    for (int i = 0; i < 2; ++i) {
      int c = i * 256 + tid;
      int row = c >> 2;
      int col = (c & 3) * 8;
      uint4 va = *(const uint4*)&FEAT[(Mtile * 128 + row) * INLEN_ + k0 + col];
      *(uint4*)&As[row * 40 + col] = va;
      uint4 vb = *(const uint4*)&W_inT[(N0 + row) * INLEN_ + k0 + col];
      *(uint4*)&Bs[row * 40 + col] = vb;
    }
    __syncthreads();
    bf16x8 af[2];
#pragma unroll
    for (int mt = 0; mt < 2; ++mt) {
      int r = wv * 32 + mt * 16 + lrow;
      af[mt] = __builtin_bit_cast(bf16x8, *(const ushortx8*)&As[r * 40 + lq * 8]);
    }
#pragma unroll
    for (int ntl = 0; ntl < 8; ++ntl) {
      bf16x8 bf = __builtin_bit_cast(bf16x8, *(const ushortx8*)&Bs[(ntl * 16 + lrow) * 40 + lq * 8]);
      acc[0][ntl] = __builtin_amdgcn_mfma_f32_16x16x32_bf16(af[0], bf, acc[0][ntl], 0, 0, 0);
      acc[1][ntl] = __builtin_amdgcn_mfma_f32_16x16x32_bf16(af[1], bf, acc[1][ntl], 0, 0, 0);
    }
    __syncthreads();
  }
#pragma unroll
  for (int mt = 0; mt < 2; ++mt)
#pragma unroll
    for (int ntl = 0; ntl < 8; ++ntl) {
      int n = N0 + ntl * 16 + lrow;
      float bias = b_in[n];
#pragma unroll
      for (int r = 0; r < 4; ++r) {
        int row = Mtile * 128 + wv * 32 + mt * 16 + lq * 4 + r;
        float v = acc[mt][ntl][r] + bias;
        v = v > 0.0f ? v : 0.0f;
        X[row * H_ + n] = f2bf(v);
      }
    }
}

// ---------------- persistent LSTM: 8 groups x 16 blocks, 512 thr ----------------
__device__ __forceinline__ void stageH(unsigned short* dst, const unsigned short* src, int tid) {
  // 16 rows x 512 shorts via agent-coherent u64 loads (bypass stale caches)
#pragma unroll
  for (int i = 0; i < 4; ++i) {
    int c = i * 512 + tid;
    int row = c >> 7;
    int col = (c & 127) * 4;
    unsigned long long v = __hip_atomic_load((const unsigned long long*)(src + row * H_ + col),
                                             __ATOMIC_RELAXED, __HIP_MEMORY_SCOPE_AGENT);
    *(unsigned long long*)&dst[row * 520 + col] = v;
  }
}
__device__ __forceinline__ void stageX(unsigned short* dst, const unsigned short* src, int tid) {
  // 16 rows x 512 shorts via regular uint4 loads (X is kernel-constant)
#pragma unroll
  for (int i = 0; i < 2; ++i) {
    int c = i * 512 + tid;
    int row = c >> 6;
    int col = (c & 63) * 8;
    uint4 v = *(const uint4*)&src[row * H_ + col];
    *(uint4*)&dst[row * 520 + col] = v;
  }
}

__device__ __forceinline__ void pollwait(const unsigned int* fp, unsigned int expect, int& guard) {
  for (;;) {
    unsigned int v = __hip_atomic_load(fp, __ATOMIC_RELAXED, __HIP_MEMORY_SCOPE_AGENT);
    if (__all((int)(v >= expect))) break;
    if (++guard > 4000000) break;   // deadlock bail -> wrong answer instead of hang
    __builtin_amdgcn_s_sleep(1);
  }
}

__global__ __launch_bounds__(512, 2) void k_lstm(
    const float* __restrict__ Wih0, const float* __restrict__ Whh0,
    const float* __restrict__ bih0, const float* __restrict__ bhh0,
    const float* __restrict__ Wih1, const float* __restrict__ Whh1,
    const float* __restrict__ bih1, const float* __restrict__ bhh1,
    const unsigned short* __restrict__ X, unsigned short* __restrict__ bufA,
    unsigned short* __restrict__ bufB, unsigned int* flagsA, unsigned int* flagsB,
    float* __restrict__ out_h, float* __restrict__ out_c) {
  __shared__ __align__(16) unsigned short hS[16 * 520];
  __shared__ __align__(16) unsigned short xS[16 * 520];
  __shared__ __align__(16) float gS[128 * 20];
  __shared__ float b0cS[128], b1cS[128];

  const int tid = threadIdx.x;
  const int group = blockIdx.x >> 4;   // 0..7 : batch rows r0..r0+15
  const int bc = blockIdx.x & 15;      // 0..15 : h-cols j0..j0+31
  const int j0 = bc * 32;
  const int r0 = group * 16;
  const int wv = tid >> 6, ln = tid & 63;
  const int lrow = ln & 15, lq = ln >> 4;
  const int n_local = wv * 16 + lrow;                              // 0..127 gate-col in block
  const int gcol = ((n_local >> 5) << 9) + j0 + (n_local & 31);    // gate*512 + hcol

  // one-time: weight B-fragments in registers (bf16), combined biases in LDS
  bf16x8 Bf0[32], Bf1[16];
  {
    const float* s0 = Wih0 + gcol * H_;
    const float* s1 = Whh0 + gcol * H_;
#pragma unroll
    for (int ks = 0; ks < 32; ++ks) {
      int k = (ks & 15) * 32 + lq * 8;
      const float* s = (ks < 16) ? (s0 + k) : (s1 + k);
      ushortx8 u;
#pragma unroll
      for (int j = 0; j < 8; ++j) u[j] = f2bf(s[j]);
      Bf0[ks] = __builtin_bit_cast(bf16x8, u);
    }
    const float* sa = Wih1 + gcol * H_;
    const float* sb = Whh1 + gcol * H_;
#pragma unroll
    for (int ks = 0; ks < 16; ++ks) {
      int k = ks * 32 + lq * 8;
      ushortx8 u;
#pragma unroll
      for (int j = 0; j < 8; ++j) u[j] = f2bf(sa[k + j] + sb[k + j]);
      Bf1[ks] = __builtin_bit_cast(bf16x8, u);
    }
  }
  if (tid < 128) {
    int g2 = ((tid >> 5) << 9) + j0 + (tid & 31);
    b0cS[tid] = bih0[g2] + bhh0[g2];
    b1cS[tid] = bih1[g2] + bhh1[g2];
  }

  unsigned int* fA = flagsA + group * 16;
  unsigned int* fB = flagsB + group * 16;
  unsigned int* myA = fA + bc;
  unsigned int* myB = fB + bc;
  const unsigned int* pollA = fA + (ln & 15);
  const unsigned int* pollB = fB + (ln & 15);

  const int eb = tid & 15, ej = tid >> 4;   // elementwise ownership: row eb, h-col j0+ej
  const int fragOff = lrow * 520 + lq * 8;
  const int lnm = ln & 15;
  float c_reg = 0.0f, cp_v = 0.0f;
  int guard = 0;

  stageX(xS, X + (0 * B_ + r0) * H_, tid);   // preload X_0
  __syncthreads();

#pragma unroll 1
  for (int t = 0; t < T_; ++t) {
    // ======== cell 0 ========
    f32x4 acc = (f32x4){0.f, 0.f, 0.f, 0.f};
#pragma unroll
    for (int ks = 0; ks < 16; ++ks) {   // x-part: independent of peers -> before poll
      bf16x8 a = __builtin_bit_cast(bf16x8, *(const ushortx8*)&xS[fragOff + ks * 32]);
      acc = __builtin_amdgcn_mfma_f32_16x16x32_bf16(a, Bf0[ks], acc, 0, 0, 0);
    }
    pollwait(pollB, (unsigned int)t, guard);   // h_{t-1} ready (t=0 trivially)
    stageH(hS, bufB + r0 * H_, tid);
    __syncthreads();
#pragma unroll
    for (int ks = 0; ks < 16; ++ks) {
      bf16x8 a = __builtin_bit_cast(bf16x8, *(const ushortx8*)&hS[fragOff + ks * 32]);
      acc = __builtin_amdgcn_mfma_f32_16x16x32_bf16(a, Bf0[16 + ks], acc, 0, 0, 0);
    }
    *(f32x4*)&gS[n_local * 20 + lq * 4] = acc;
    __syncthreads();
    float hv;
    {
      float iv = gS[(ej) * 20 + eb] + b0cS[ej];
      float fv = gS[(32 + ej) * 20 + eb] + b0cS[32 + ej];
      float gv = gS[(64 + ej) * 20 + eb] + b0cS[64 + ej];
      float ov = gS[(96 + ej) * 20 + eb] + b0cS[96 + ej];
      cp_v = sigm(fv) * c_reg + sigm(iv) * tanhf_(gv);
      hv = sigm(ov) * tanhf_(cp_v);
    }
    {  // pack 4 h-cols per row via shfl; lanes 0..15 store u64 to bufA
      float p0 = __shfl(hv, lnm, 64);
      float p1 = __shfl(hv, lnm + 16, 64);
      float p2 = __shfl(hv, lnm + 32, 64);
      float p3 = __shfl(hv, lnm + 48, 64);
      if (ln < 16) {
        unsigned long long v = (unsigned long long)f2bf(p0) |
                               ((unsigned long long)f2bf(p1) << 16) |
                               ((unsigned long long)f2bf(p2) << 32) |
                               ((unsigned long long)f2bf(p3) << 48);
        __hip_atomic_store((unsigned long long*)(bufA + (r0 + lnm) * H_ + j0 + wv * 4), v,
                           __ATOMIC_RELAXED, __HIP_MEMORY_SCOPE_AGENT);
      }
    }
    __syncthreads();   // compiler drains vmcnt before s_barrier -> stores at coherence point
    if (tid == 0) __hip_atomic_store(myA, (unsigned int)(t + 1), __ATOMIC_RELAXED,
                                     __HIP_MEMORY_SCOPE_AGENT);

    // ======== cell 1 ========
    if (t + 1 < T_) stageX(xS, X + ((t + 1) * B_ + r0) * H_, tid);   // prefetch next X
    pollwait(pollA, (unsigned int)(t + 1), guard);
    stageH(hS, bufA + r0 * H_, tid);
    __syncthreads();
    acc = (f32x4){0.f, 0.f, 0.f, 0.f};
#pragma unroll
    for (int ks = 0; ks < 16; ++ks) {
      bf16x8 a = __builtin_bit_cast(bf16x8, *(const ushortx8*)&hS[fragOff + ks * 32]);
      acc = __builtin_amdgcn_mfma_f32_16x16x32_bf16(a, Bf1[ks], acc, 0, 0, 0);
    }
    *(f32x4*)&gS[n_local * 20 + lq * 4] = acc;
    __syncthreads();
    {
      float iv = gS[(ej) * 20 + eb] + b1cS[ej];
      float fv = gS[(32 + ej) * 20 + eb] + b1cS[32 + ej];
      float gv = gS[(64 + ej) * 20 + eb] + b1cS[64 + ej];
      float ov = gS[(96 + ej) * 20 + eb] + b1cS[96 + ej];
      float cn = sigm(fv) * cp_v + sigm(iv) * tanhf_(gv);
      hv = sigm(ov) * tanhf_(cn);
      c_reg = cn;
      if (t == T_ - 1) {
        out_h[(r0 + eb) * H_ + j0 + ej] = hv;
        out_c[(r0 + eb) * H_ + j0 + ej] = cn;
      }
    }
    {
      float p0 = __shfl(hv, lnm, 64);
      float p1 = __shfl(hv, lnm + 16, 64);
      float p2 = __shfl(hv, lnm + 32, 64);
      float p3 = __shfl(hv, lnm + 48, 64);
      if (ln < 16) {
        unsigned long long v = (unsigned long long)f2bf(p0) |
                               ((unsigned long long)f2bf(p1) << 16) |
                               ((unsigned long long)f2bf(p2) << 32) |
                               ((unsigned long long)f2bf(p3) << 48);
        __hip_atomic_store((unsigned long long*)(bufB + (r0 + lnm) * H_ + j0 + wv * 4), v,
                           __ATOMIC_RELAXED, __HIP_MEMORY_SCOPE_AGENT);
      }
    }
    __syncthreads();
    if (tid == 0) __hip_atomic_store(myB, (unsigned int)(t + 1), __ATOMIC_RELAXED,
                                     __HIP_MEMORY_SCOPE_AGENT);
  }
}

// ---------------- heads: cont_out + cls_out (f32) ----------------
__global__ __launch_bounds__(256) void k_heads(const float* __restrict__ h,
                                               const float* __restrict__ W_out,
                                               const float* __restrict__ b_out,
                                               const float* __restrict__ W_cls,
                                               const float* __restrict__ b_cls,
                                               float* __restrict__ out) {
  int o = blockIdx.x * 256 + threadIdx.x;
  if (o < B_ * NCONT_) {
    int b = o / NCONT_;
    int n = o - b * NCONT_;
    float acc = b_out[n];
    const float* hb = h + b * H_;
    for (int k = 0; k < H_; k += 4) {
      acc += hb[k] * W_out[k * NCONT_ + n] + hb[k + 1] * W_out[(k + 1) * NCONT_ + n] +
             hb[k + 2] * W_out[(k + 2) * NCONT_ + n] + hb[k + 3] * W_out[(k + 3) * NCONT_ + n];
    }
    out[o] = acc;
  } else {
    int oo = o - B_ * NCONT_;
    int b = oo >> 9;
    int r = oo & 511;
    int ci = r >> 4, cd = r & 15;
    float acc = b_cls[ci * 16 + cd];
    const float* hb = h + b * H_;
    const float* wc = W_cls + ci * 512 * 16 + cd;
    for (int k = 0; k < H_; k += 4) {
      acc += hb[k] * wc[k * 16] + hb[k + 1] * wc[(k + 1) * 16] + hb[k + 2] * wc[(k + 2) * 16] +
             hb[k + 3] * wc[(k + 3) * 16];
    }
    out[B_ * NCONT_ + oo] = acc;
  }
}

extern "C" void kernel_launch(void* const* d_in, const int* in_sizes, int n_in,
                              void* d_out, int out_size, void* d_ws, size_t ws_size,
                              hipStream_t stream) {
  const int* unscaled = (const int*)d_in[0];
  const float* scaled = (const float*)d_in[1];
  const float* emb = (const float*)d_in[2];
  const float* W_in = (const float*)d_in[3];
  const float* b_in = (const float*)d_in[4];
  const float* Wih0 = (const float*)d_in[5];
  const float* Whh0 = (const float*)d_in[6];
  const float* bih0 = (const float*)d_in[7];
  const float* bhh0 = (const float*)d_in[8];
  const float* Wih1 = (const float*)d_in[9];
  const float* Whh1 = (const float*)d_in[10];
  const float* bih1 = (const float*)d_in[11];
  const float* bhh1 = (const float*)d_in[12];
  const float* W_out = (const float*)d_in[13];
  const float* b_out = (const float*)d_in[14];
  const float* W_cls = (const float*)d_in[15];
  const float* b_cls = (const float*)d_in[16];

  const size_t o_feat = 0;                       // 23068672
  const size_t o_X = 23068672;                   // 33554432
  const size_t o_WinT = 56623104;                // 360448
  const size_t o_bufA = 56983552;                // 131072
  const size_t o_bufB = 57114624;                // 131072
  const size_t o_flag = 57245696;                // 1024
  const size_t WS_NEED = 57246720;
  if (ws_size < WS_NEED) return;

  char* ws = (char*)d_ws;
  unsigned short* FEAT = (unsigned short*)(ws + o_feat);
  unsigned short* X = (unsigned short*)(ws + o_X);
  unsigned short* W_inT = (unsigned short*)(ws + o_WinT);
  unsigned short* bufA = (unsigned short*)(ws + o_bufA);
  unsigned short* bufB = (unsigned short*)(ws + o_bufB);
  unsigned int* flags = (unsigned int*)(ws + o_flag);
  unsigned int* flagsA = flags;
  unsigned int* flagsB = flags + 128;

  float* out = (float*)d_out;
  float* out_h = out + 77824;
  float* out_c = out + 143360;

  k_init<<<129, 256, 0, stream>>>((unsigned int*)bufB, flags);
  k_prep<<<704, 256, 0, stream>>>(W_in, W_inT);
  k_feat<<<8192, 256, 0, stream>>>(unscaled, scaled, emb, FEAT);
  k_gemm1<<<1024, 256, 0, stream>>>(FEAT, W_inT, b_in, X);
  k_lstm<<<128, 512, 0, stream>>>(Wih0, Whh0, bih0, bhh0, Wih1, Whh1, bih1, bhh1, X, bufA, bufB,
                                  flagsA, flagsB, out_h, out_c);
  k_heads<<<304, 256, 0, stream>>>(out_h, W_out, b_out, W_cls, b_cls, out);
}